// Round 2
// baseline (1604.231 us; speedup 1.0000x reference)
//
#include <hip/hip_runtime.h>
#include <math.h>

// HeterogeneousGNN fused kernel for MI355X (gfx950) — round 2.
// One workgroup (512 thr = 8 waves) per batch element; H[b] (256x128 bf16,
// swizzled) resident in LDS across all 3 layers. Per layer, per half h, the
// intermediate G = H @ W^T is computed in v-chunks of 64 nodes (Gc = 16 KB)
// so total LDS = 80 KB -> 2 blocks/CU. GEMM2 (acc += A_h @ G) accumulates
// partial-k per chunk; adjacency is read exactly once per half (k-partitioned).
// GEMM1 wave tile 32x32 keeps gacc at 16 VGPRs so acc[2][8] (64 VGPR) never
// spills (round-1 failure mode: 1.3 GB of scratch writes).

typedef float  f32x4  __attribute__((ext_vector_type(4)));
typedef short  s16x8  __attribute__((ext_vector_type(8)));
typedef __bf16 bf16x8 __attribute__((ext_vector_type(8)));

#define NNODE 256
#define DIMF  128
#define HBYTES 65536

__device__ __forceinline__ unsigned short f2bf(float f) {
  unsigned int u = __builtin_bit_cast(unsigned int, f);
  u = (u + 0x7fffu + ((u >> 16) & 1u)) >> 16;   // round-to-nearest-even
  return (unsigned short)u;
}
__device__ __forceinline__ float bf2f(unsigned short h) {
  return __builtin_bit_cast(float, (unsigned int)h << 16);
}

// XOR-swizzled LDS byte addresses (T2): row-stride patterns would otherwise be
// 16-32-way bank conflicts on ds_read_b128.
__device__ __forceinline__ int haddr(int v, int d) {   // H: [256 v][128 d] bf16
  return v * 256 + ((d * 2) ^ ((v & 7) << 4));
}
__device__ __forceinline__ int gaddr(int o, int vc) {  // Gc^T: [128 o][64 v] bf16
  return HBYTES + o * 128 + ((vc * 2) ^ ((o & 7) << 4));
}

#define MFMA16(a, b, c) __builtin_amdgcn_mfma_f32_16x16x32_bf16( \
    __builtin_bit_cast(bf16x8, (a)), __builtin_bit_cast(bf16x8, (b)), (c), 0, 0, 0)

// ---- prep: sigmoid+mask adjacency -> bf16 (neg sign folded), W -> bf16 ----
__global__ void prep_kernel(const float* __restrict__ alp, const float* __restrict__ aln,
                            const float* __restrict__ wp,  const float* __restrict__ wn,
                            unsigned short* __restrict__ A2, unsigned short* __restrict__ W2) {
  int idx = blockIdx.x * 512 + threadIdx.x;            // 163840 threads total
  if (idx < 65536) {
    float ap = 1.f / (1.f + expf(-alp[idx]));
    float an = 1.f / (1.f + expf(-aln[idx]));
    bool  m  = ap > an;
    A2[idx]          = f2bf(m ? ap : 0.f);
    A2[65536 + idx]  = f2bf(m ? 0.f : -an);            // sign folded: GEMM2 always adds
  } else {
    int j = idx - 65536;                               // 0 .. 98303
    int l = j >> 15;
    int h = (j >> 14) & 1;
    int e = j & 16383;
    const float* src = h ? wn : wp;
    W2[j] = f2bf(src[l * 16384 + e]);
  }
}

__global__ __launch_bounds__(512, 4) void gnn_kernel(
    const float* __restrict__ X,
    const unsigned short* __restrict__ A2,
    const unsigned short* __restrict__ W2,
    const float* __restrict__ ln_g, const float* __restrict__ ln_b,
    const float* __restrict__ ro_g, const float* __restrict__ ro_b,
    float* __restrict__ out) {
  extern __shared__ char smem[];
  const int tid  = threadIdx.x;
  const int wid  = tid >> 6;
  const int lane = tid & 63;
  const int g    = lane >> 4;       // k-group 0..3
  const int r16  = lane & 15;
  const int b    = blockIdx.x;
  const int rg   = wid >> 2;        // GEMM1 row-group (v), 0..1
  const int cg   = wid & 3;         // GEMM1 col-group (o), 0..3

  // ---- stage H = bf16(X[b]) into LDS (swizzled) ----
  {
    const float4* Xb = (const float4*)(X + (size_t)b * NNODE * DIMF);
#pragma unroll
    for (int i = 0; i < 16; ++i) {
      int idx = tid + i * 512;                // 8192 float4 chunks
      int v   = idx >> 5;
      int d   = (idx & 31) * 4;
      float4 f = Xb[idx];
      ushort4 p;
      p.x = f2bf(f.x); p.y = f2bf(f.y); p.z = f2bf(f.z); p.w = f2bf(f.w);
      *(ushort4*)(smem + haddr(v, d)) = p;
    }
  }
  __syncthreads();

  f32x4 acc[2][8];                             // 32 rows x 128 cols / wave
  const f32x4 fzero = {0.f, 0.f, 0.f, 0.f};

  for (int l = 0; l < 3; ++l) {
#pragma unroll
    for (int rt = 0; rt < 2; ++rt)
#pragma unroll
      for (int ct = 0; ct < 8; ++ct) acc[rt][ct] = fzero;

    for (int h = 0; h < 2; ++h) {
      const unsigned short* Wl = W2 + (l * 2 + h) * DIMF * DIMF;
      const unsigned short* Ah = A2 + h * NNODE * NNODE;

      for (int c = 0; c < 4; ++c) {            // v-chunks of 64 nodes
        // ---- GEMM1 chunk: Gc[v in 64c..64c+64][o 0..128] = H @ Wl^T ----
        // wave tile: v rows [c*64 + rg*32, +32), o cols [cg*32, +32)
        const int v0 = c * 64 + rg * 32;
        const int o0 = cg * 32;
        f32x4 gacc[2][2];
#pragma unroll
        for (int mt = 0; mt < 2; ++mt)
#pragma unroll
          for (int nt = 0; nt < 2; ++nt) gacc[mt][nt] = fzero;

#pragma unroll
        for (int kk = 0; kk < 4; ++kk) {       // k = d, 128 = 4 x 32
          s16x8 haf[2], wbf[2];
#pragma unroll
          for (int mt = 0; mt < 2; ++mt)
            haf[mt] = *(const s16x8*)(smem + haddr(v0 + mt * 16 + r16, kk * 32 + g * 8));
#pragma unroll
          for (int nt = 0; nt < 2; ++nt)
            wbf[nt] = *(const s16x8*)(Wl + (o0 + nt * 16 + r16) * DIMF + kk * 32 + g * 8);
#pragma unroll
          for (int mt = 0; mt < 2; ++mt)
#pragma unroll
            for (int nt = 0; nt < 2; ++nt)
              gacc[mt][nt] = MFMA16(haf[mt], wbf[nt], gacc[mt][nt]);
        }
        __syncthreads();   // prior GEMM2 chunk done reading Gc
        // store Gc^T[o][vrel]; C/D layout: col o = r16 part, rows v = g*4+reg
#pragma unroll
        for (int mt = 0; mt < 2; ++mt)
#pragma unroll
          for (int nt = 0; nt < 2; ++nt) {
            int o  = o0 + nt * 16 + r16;
            int vc = rg * 32 + mt * 16 + g * 4;
            ushort4 p;
            p.x = f2bf(gacc[mt][nt][0]);
            p.y = f2bf(gacc[mt][nt][1]);
            p.z = f2bf(gacc[mt][nt][2]);
            p.w = f2bf(gacc[mt][nt][3]);
            *(ushort4*)(smem + gaddr(o, vc)) = p;
          }
        __syncthreads();

        // ---- GEMM2 partial-k: acc += Ah[u, 64c..64c+64] @ Gc ----
#pragma unroll
        for (int kk = 0; kk < 2; ++kk) {       // 64 = 2 x 32
          s16x8 aaf[2], gbf[8];
#pragma unroll
          for (int rt = 0; rt < 2; ++rt)
            aaf[rt] = *(const s16x8*)(Ah + (wid * 32 + rt * 16 + r16) * NNODE
                                      + c * 64 + kk * 32 + g * 8);
#pragma unroll
          for (int ct = 0; ct < 8; ++ct)
            gbf[ct] = *(const s16x8*)(smem + gaddr(ct * 16 + r16, kk * 32 + g * 8));
#pragma unroll
          for (int rt = 0; rt < 2; ++rt)
#pragma unroll
            for (int ct = 0; ct < 8; ++ct)
              acc[rt][ct] = MFMA16(aaf[rt], gbf[ct], acc[rt][ct]);
        }
      } // chunks
    } // halves

    // ---- epilogue: exact GELU + LayerNorm -> H (bf16) ----
    // (H reads for this layer all completed before the last chunk's store-sync)
    float lg[8], lb[8];
#pragma unroll
    for (int ct = 0; ct < 8; ++ct) {
      lg[ct] = ln_g[l * DIMF + ct * 16 + r16];
      lb[ct] = ln_b[l * DIMF + ct * 16 + r16];
    }
#pragma unroll
    for (int rt = 0; rt < 2; ++rt)
#pragma unroll
      for (int ct = 0; ct < 8; ++ct)
#pragma unroll
        for (int r = 0; r < 4; ++r) {
          float x = acc[rt][ct][r];
          acc[rt][ct][r] = 0.5f * x * (1.f + erff(x * 0.70710678f));
        }
#pragma unroll
    for (int rt = 0; rt < 2; ++rt)
#pragma unroll
      for (int r = 0; r < 4; ++r) {
        float s1 = 0.f, s2 = 0.f;
#pragma unroll
        for (int ct = 0; ct < 8; ++ct) {
          float v = acc[rt][ct][r];
          s1 += v; s2 += v * v;
        }
#pragma unroll
        for (int m = 1; m < 16; m <<= 1) {     // 16-lane row-group reduce
          s1 += __shfl_xor(s1, m);
          s2 += __shfl_xor(s2, m);
        }
        float mu  = s1 * (1.f / 128.f);
        float var = s2 * (1.f / 128.f) - mu * mu;
        float rs  = rsqrtf(var + 1e-5f);
        int row = wid * 32 + rt * 16 + g * 4 + r;
#pragma unroll
        for (int ct = 0; ct < 8; ++ct) {
          float y = (acc[rt][ct][r] - mu) * rs * lg[ct] + lb[ct];
          *(unsigned short*)(smem + haddr(row, ct * 16 + r16)) = f2bf(y);
        }
      }
    __syncthreads();   // H fully updated before next layer's GEMM1
  }

  // ---- readout: mean over nodes + final LN ----
  {
    int d   = tid & 127;
    int grp = tid >> 7;
    float s = 0.f;
    for (int v = grp * 64; v < grp * 64 + 64; ++v)
      s += bf2f(*(const unsigned short*)(smem + haddr(v, d)));
    float* red = (float*)(smem + HBYTES);      // Gc region is dead now
    red[grp * 128 + d] = s;
    __syncthreads();
    if (tid < 128) {
      float hv = (red[tid] + red[128 + tid] + red[256 + tid] + red[384 + tid]) * (1.f / 256.f);
      red[512 + tid] = hv;
    }
    __syncthreads();
    if (tid < 64) {
      float a  = red[512 + tid];
      float b2 = red[512 + 64 + tid];
      float s1 = a + b2, s2 = a * a + b2 * b2;
#pragma unroll
      for (int m = 1; m < 64; m <<= 1) {
        s1 += __shfl_xor(s1, m);
        s2 += __shfl_xor(s2, m);
      }
      float mu  = s1 * (1.f / 128.f);
      float var = s2 * (1.f / 128.f) - mu * mu;
      float rs  = rsqrtf(var + 1e-5f);
      out[(size_t)b * 128 + tid]      = (a  - mu) * rs * ro_g[tid]      + ro_b[tid];
      out[(size_t)b * 128 + 64 + tid] = (b2 - mu) * rs * ro_g[64 + tid] + ro_b[64 + tid];
    }
  }
}

extern "C" void kernel_launch(void* const* d_in, const int* in_sizes, int n_in,
                              void* d_out, int out_size, void* d_ws, size_t ws_size,
                              hipStream_t stream) {
  const float* X   = (const float*)d_in[0];
  const float* alp = (const float*)d_in[1];
  const float* aln = (const float*)d_in[2];
  const float* wp  = (const float*)d_in[3];
  const float* wn  = (const float*)d_in[4];
  const float* lng = (const float*)d_in[5];
  const float* lnb = (const float*)d_in[6];
  const float* rog = (const float*)d_in[7];
  const float* rob = (const float*)d_in[8];
  float* out = (float*)d_out;

  unsigned short* A2 = (unsigned short*)d_ws;          // 2*65536 bf16 = 256 KB
  unsigned short* W2 = A2 + 2 * 65536;                 // 6*16384 bf16 = 192 KB

  (void)hipFuncSetAttribute(reinterpret_cast<const void*>(gnn_kernel),
                            hipFuncAttributeMaxDynamicSharedMemorySize, 81920);

  prep_kernel<<<320, 512, 0, stream>>>(alp, aln, wp, wn, A2, W2);
  gnn_kernel<<<2048, 512, 81920, stream>>>(X, A2, W2, lng, lnb, rog, rob, out);
}